// Round 1
// baseline (254.051 us; speedup 1.0000x reference)
//
#include <hip/hip_runtime.h>
#include <hip/hip_bf16.h>

// Problem constants (B=4, S=2048, D=512, H=8, Dh=64)
#define BATCH 4
#define SEQ   2048
#define DIM   512
#define NH    8
#define DH    64
#define NTOK  (BATCH*SEQ)        // 8192

typedef __bf16 bf16x8 __attribute__((ext_vector_type(8)));
typedef float  f32x4  __attribute__((ext_vector_type(4)));

#define MFMA16(a,b,c) __builtin_amdgcn_mfma_f32_16x16x32_bf16((a),(b),(c),0,0,0)

#if __has_builtin(__builtin_amdgcn_exp2f)
#define EXP2F(x) __builtin_amdgcn_exp2f(x)
#else
#define EXP2F(x) exp2f(x)
#endif

// Q is pre-scaled by log2(e)/8 in the projection epilogue -> softmax in exp2 space
#define QSCALE 0.18033688011112042f

// async global->LDS, 16 B per lane; LDS dest must be wave-uniform base (+lane*16)
typedef __attribute__((address_space(1))) void GAS;
typedef __attribute__((address_space(3))) void LAS;
__device__ __forceinline__ void gl_lds16(const void* g, void* l) {
  __builtin_amdgcn_global_load_lds((GAS*)g, (LAS*)l, 16, 0, 0);
}

// ---------------------------------------------------------------------------
// fp32 -> bf16 convert, 8 elems/thread
// ---------------------------------------------------------------------------
__global__ __launch_bounds__(256) void cvt_f32_bf16(const float* __restrict__ src,
                                                    __bf16* __restrict__ dst, int n8) {
  int i = blockIdx.x * blockDim.x + threadIdx.x;
  if (i >= n8) return;
  const float4* s = (const float4*)src;
  float4 a = s[2*i], b = s[2*i+1];
  bf16x8 o;
  o[0] = (__bf16)a.x; o[1] = (__bf16)a.y; o[2] = (__bf16)a.z; o[3] = (__bf16)a.w;
  o[4] = (__bf16)b.x; o[5] = (__bf16)b.y; o[6] = (__bf16)b.z; o[7] = (__bf16)b.w;
  *(bf16x8*)&dst[8*i] = o;
}

__global__ __launch_bounds__(256) void cvt_weights(
    const float* __restrict__ s0, const float* __restrict__ s1,
    const float* __restrict__ s2, const float* __restrict__ s3,
    __bf16* __restrict__ o0, __bf16* __restrict__ o1,
    __bf16* __restrict__ o2, __bf16* __restrict__ o3) {
  int i = blockIdx.x * blockDim.x + threadIdx.x;   // 4 * 32768 chunks of 8
  const int which = i >> 15, off = i & 32767;
  const float* src = (which == 0) ? s0 : (which == 1) ? s1 : (which == 2) ? s2 : s3;
  __bf16* dst      = (which == 0) ? o0 : (which == 1) ? o1 : (which == 2) ? o2 : o3;
  const float4* s = (const float4*)src;
  float4 a = s[2*off], b = s[2*off+1];
  bf16x8 o;
  o[0] = (__bf16)a.x; o[1] = (__bf16)a.y; o[2] = (__bf16)a.z; o[3] = (__bf16)a.w;
  o[4] = (__bf16)b.x; o[5] = (__bf16)b.y; o[6] = (__bf16)b.z; o[7] = (__bf16)b.w;
  *(bf16x8*)&dst[8*off] = o;
}

// ---------------------------------------------------------------------------
// NT GEMM 128x128 tile, m97 structure: global_load_lds (16B) into linear
// LDS [128][64], 4 waves, 4x4 acc/wave.  z = 0/1/2 -> Q / K / V projection.
// Q written pre-scaled by log2e/8 (exp2-space softmax downstream).
// ---------------------------------------------------------------------------
__global__ __launch_bounds__(256) void gemm_qkv(
    const __bf16* __restrict__ xb,
    const __bf16* __restrict__ wq, const __bf16* __restrict__ wk,
    const __bf16* __restrict__ wv,
    const float* __restrict__ bq, const float* __restrict__ bk,
    const float* __restrict__ bv,
    __bf16* __restrict__ Qb, __bf16* __restrict__ Kb, __bf16* __restrict__ Vt)
{
  const int z = blockIdx.z;
  const __bf16* W    = (z == 0) ? wq : (z == 1) ? wk : wv;
  const float*  bias = (z == 0) ? bq : (z == 1) ? bk : bv;

  __shared__ __align__(16) __bf16 As[128*64];
  __shared__ __align__(16) __bf16 Bs[128*64];

  const int tid  = threadIdx.x;
  const int m0   = blockIdx.x * 128, n0 = blockIdx.y * 128;
  const int w    = tid >> 6, lane = tid & 63, quad = lane >> 4, l16 = lane & 15;
  const int wm   = (w >> 1) * 64, wn = (w & 1) * 64;
  // staging: chunk = (w*4+i)*64 + lane ; row = chunk>>3 ; col16B = lane&7
  const int srow = w*32 + (lane >> 3);
  const int scc  = (lane & 7) * 8;

  f32x4 acc[4][4] = {};

  for (int k0 = 0; k0 < DIM; k0 += 64) {
#pragma unroll
    for (int i = 0; i < 4; ++i) {
      const int row = srow + i*8;
      gl_lds16(&xb[(size_t)(m0+row)*DIM + k0 + scc], &As[(w*4+i)*512]);
      gl_lds16(&W [(size_t)(n0+row)*DIM + k0 + scc], &Bs[(w*4+i)*512]);
    }
    __syncthreads();
#pragma unroll
    for (int kk = 0; kk < 2; ++kk) {
      const int ko = kk*32 + quad*8;
      bf16x8 af[4], bfr[4];
#pragma unroll
      for (int f = 0; f < 4; ++f) {
        af[f]  = *(const bf16x8*)&As[(wm + f*16 + l16)*64 + ko];
        bfr[f] = *(const bf16x8*)&Bs[(wn + f*16 + l16)*64 + ko];
      }
#pragma unroll
      for (int fm = 0; fm < 4; ++fm)
#pragma unroll
        for (int fn = 0; fn < 4; ++fn)
          acc[fm][fn] = MFMA16(af[fm], bfr[fn], acc[fm][fn]);
    }
    __syncthreads();
  }

  // epilogue: C row = m0+wm+fm*16+quad*4+r ; col = n0+wn+fn*16+l16
#pragma unroll
  for (int fm = 0; fm < 4; ++fm) {
#pragma unroll
    for (int fn = 0; fn < 4; ++fn) {
      const int col  = n0 + wn + fn*16 + l16;
      const float bc = bias[col];
      const int h = col >> 6, dh = col & 63;
#pragma unroll
      for (int r = 0; r < 4; ++r) {
        const int row = m0 + wm + fm*16 + quad*4 + r;
        const int b = row >> 11, s = row & 2047;
        const float v = acc[fm][fn][r] + bc;
        if (z == 2) {
          Vt[((size_t)(b*NH + h)*DH + dh)*SEQ + s] = (__bf16)v;
        } else if (z == 0) {
          Qb[((size_t)(b*NH + h)*SEQ + s)*DH + dh] = (__bf16)(v * QSCALE);
        } else {
          Kb[((size_t)(b*NH + h)*SEQ + s)*DH + dh] = (__bf16)v;
        }
      }
    }
  }
}

// ---------------------------------------------------------------------------
// Output projection (same m97-style staging), fp32 out
// ---------------------------------------------------------------------------
__global__ __launch_bounds__(256) void gemm_out(
    const __bf16* __restrict__ attnb, const __bf16* __restrict__ wo,
    const float* __restrict__ bo, float* __restrict__ out)
{
  __shared__ __align__(16) __bf16 As[128*64];
  __shared__ __align__(16) __bf16 Bs[128*64];

  const int tid = threadIdx.x;
  const int m0  = blockIdx.x * 128, n0 = blockIdx.y * 128;
  const int w   = tid >> 6, lane = tid & 63, quad = lane >> 4, l16 = lane & 15;
  const int wm  = (w >> 1) * 64, wn = (w & 1) * 64;
  const int srow = w*32 + (lane >> 3);
  const int scc  = (lane & 7) * 8;

  f32x4 acc[4][4] = {};

  for (int k0 = 0; k0 < DIM; k0 += 64) {
#pragma unroll
    for (int i = 0; i < 4; ++i) {
      const int row = srow + i*8;
      gl_lds16(&attnb[(size_t)(m0+row)*DIM + k0 + scc], &As[(w*4+i)*512]);
      gl_lds16(&wo   [(size_t)(n0+row)*DIM + k0 + scc], &Bs[(w*4+i)*512]);
    }
    __syncthreads();
#pragma unroll
    for (int kk = 0; kk < 2; ++kk) {
      const int ko = kk*32 + quad*8;
      bf16x8 af[4], bfr[4];
#pragma unroll
      for (int f = 0; f < 4; ++f) {
        af[f]  = *(const bf16x8*)&As[(wm + f*16 + l16)*64 + ko];
        bfr[f] = *(const bf16x8*)&Bs[(wn + f*16 + l16)*64 + ko];
      }
#pragma unroll
      for (int fm = 0; fm < 4; ++fm)
#pragma unroll
        for (int fn = 0; fn < 4; ++fn)
          acc[fm][fn] = MFMA16(af[fm], bfr[fn], acc[fm][fn]);
    }
    __syncthreads();
  }

#pragma unroll
  for (int fm = 0; fm < 4; ++fm) {
#pragma unroll
    for (int fn = 0; fn < 4; ++fn) {
      const int col  = n0 + wn + fn*16 + l16;
      const float bc = bo[col];
#pragma unroll
      for (int r = 0; r < 4; ++r) {
        const int row = m0 + wm + fm*16 + quad*4 + r;
        out[(size_t)row*DIM + col] = acc[fm][fn][r] + bc;
      }
    }
  }
}

// ---------------------------------------------------------------------------
// Flash attention v4: split-K across 4 waves per block (occupancy fix).
// 2048 blocks x 256 thr; block = (bh, 32-row q-tile); wave w does k-tiles
// w, w+4, w+8, ...  Private online-softmax state per wave (exp2 domain,
// Q pre-scaled by log2e/8), K register double-buffer, V issued early.
// End: waves 1-3 dump (m,l,of) to LDS, wave 0 merges + stores.
// ---------------------------------------------------------------------------
__global__ __launch_bounds__(256) void flash_attn(
    const __bf16* __restrict__ Qb, const __bf16* __restrict__ Kb,
    const __bf16* __restrict__ Vt, __bf16* __restrict__ attnb)
{
  const int idx = blockIdx.x;
  const int bh  = idx & 31;                    // spread heads across XCDs
  const int t   = 63 - (idx >> 5);             // heavy q-tiles dispatch first
  const int b   = bh >> 3, h = bh & 7;
  const int tid = threadIdx.x;
  const int wv  = tid >> 6;                    // wave 0..3 (split-K)
  const int lane = tid & 63, quad = lane >> 4, l16 = lane & 15;
  const int q0  = t * 32;

  const __bf16* Qp = Qb + (size_t)bh * SEQ * DH;   // [s][dh], pre-scaled
  const __bf16* Kp = Kb + (size_t)bh * SEQ * DH;   // [s][dh]
  const __bf16* Vp = Vt + (size_t)bh * DH * SEQ;   // [dh][s]

  // union: per-wave P patch (4 x 4608 B) | combine buffer (3 x 64 x 52 f32)
  __shared__ __align__(16) char smem[3*64*52*4];
  __bf16* Pw = (__bf16*)(smem + wv*4608);          // 32 x 72 bf16 per wave

  // Q fragments (already scaled by log2e/8 at projection)
  bf16x8 qf[2][2];
#pragma unroll
  for (int mf = 0; mf < 2; ++mf)
#pragma unroll
    for (int kk = 0; kk < 2; ++kk)
      qf[mf][kk] = *(const bf16x8*)&Qp[(size_t)(q0 + mf*16 + l16)*DH + kk*32 + quad*8];

  f32x4 of[2][4] = {};
  float m_[2][4], l_[2][4];
#pragma unroll
  for (int mf = 0; mf < 2; ++mf)
#pragma unroll
    for (int r = 0; r < 4; ++r) { m_[mf][r] = -1e30f; l_[mf][r] = 0.f; }

  const int ktiles = (q0 >> 6) + 1;            // covers keys [0, q0+32)

  bf16x8 kfA[4][2], kfB[4][2];
  // prologue: this wave's first K tile (tile index = wv; always in-bounds mem)
#pragma unroll
  for (int fn = 0; fn < 4; ++fn)
#pragma unroll
    for (int kk = 0; kk < 2; ++kk)
      kfA[fn][kk] = *(const bf16x8*)&Kp[(size_t)(wv*64 + fn*16 + l16)*DH + kk*32 + quad*8];

#define TILE_STEP(KC, KN, KT)                                                  \
  {                                                                            \
    const int k0 = (KT) * 64;                                                  \
    /* V for this tile — issued first, consumed after softmax */               \
    bf16x8 vf[4][2];                                                           \
    _Pragma("unroll")                                                          \
    for (int nd = 0; nd < 4; ++nd)                                             \
      _Pragma("unroll")                                                        \
      for (int kq = 0; kq < 2; ++kq)                                           \
        vf[nd][kq] = *(const bf16x8*)&Vp[(size_t)(nd*16 + l16)*SEQ + k0 +      \
                                         kq*32 + quad*8];                      \
    /* prefetch this wave's next K tile (stride 4) into the other buffer */    \
    {                                                                          \
      const int kn0 = ((KT) + 4 < ktiles) ? k0 + 256 : 0;                      \
      _Pragma("unroll")                                                        \
      for (int fn = 0; fn < 4; ++fn)                                           \
        _Pragma("unroll")                                                      \
        for (int kk = 0; kk < 2; ++kk)                                         \
          KN[fn][kk] = *(const bf16x8*)&Kp[(size_t)(kn0 + fn*16 + l16)*DH +    \
                                           kk*32 + quad*8];                    \
    }                                                                          \
    /* QK^T (16 MFMAs), scores in log2 domain */                               \
    f32x4 sf[2][4] = {};                                                       \
    _Pragma("unroll")                                                          \
    for (int mf = 0; mf < 2; ++mf)                                             \
      _Pragma("unroll")                                                        \
      for (int fn = 0; fn < 4; ++fn) {                                         \
        sf[mf][fn] = MFMA16(qf[mf][0], KC[fn][0], sf[mf][fn]);                 \
        sf[mf][fn] = MFMA16(qf[mf][1], KC[fn][1], sf[mf][fn]);                 \
      }                                                                        \
    /* causal mask (only diagonal-crossing tiles) */                           \
    if (k0 + 63 > q0) {                                                        \
      _Pragma("unroll")                                                        \
      for (int mf = 0; mf < 2; ++mf)                                           \
        _Pragma("unroll")                                                      \
        for (int fn = 0; fn < 4; ++fn) {                                       \
          const int col = k0 + fn*16 + l16;                                    \
          _Pragma("unroll")                                                    \
          for (int r = 0; r < 4; ++r) {                                        \
            const int row = q0 + mf*16 + quad*4 + r;                           \
            if (col > row) sf[mf][fn][r] = -1e30f;                             \
          }                                                                    \
        }                                                                      \
    }                                                                          \
    /* online softmax (exp2 space) over 8 (mf,r) rows */                       \
    float rmax[2][4];                                                          \
    _Pragma("unroll")                                                          \
    for (int mf = 0; mf < 2; ++mf)                                             \
      _Pragma("unroll")                                                        \
      for (int r = 0; r < 4; ++r)                                              \
        rmax[mf][r] = fmaxf(fmaxf(sf[mf][0][r], sf[mf][1][r]),                 \
                            fmaxf(sf[mf][2][r], sf[mf][3][r]));                \
    _Pragma("unroll")                                                          \
    for (int d = 1; d < 16; d <<= 1)                                           \
      _Pragma("unroll")                                                        \
      for (int mf = 0; mf < 2; ++mf)                                           \
        _Pragma("unroll")                                                      \
        for (int r = 0; r < 4; ++r)                                            \
          rmax[mf][r] = fmaxf(rmax[mf][r], __shfl_xor(rmax[mf][r], d));        \
    _Pragma("unroll")                                                          \
    for (int mf = 0; mf < 2; ++mf)                                             \
      _Pragma("unroll")                                                        \
      for (int r = 0; r < 4; ++r) {                                            \
        const float mn = fmaxf(m_[mf][r], rmax[mf][r]);                        \
        const float al = EXP2F(m_[mf][r] - mn);                                \
        m_[mf][r] = mn;                                                        \
        l_[mf][r] *= al;                                                       \
        _Pragma("unroll")                                                      \
        for (int nd = 0; nd < 4; ++nd) of[mf][nd][r] *= al;                    \
      }                                                                        \
    _Pragma("unroll")                                                          \
    for (int mf = 0; mf < 2; ++mf)                                             \
      _Pragma("unroll")                                                        \
      for (int fn = 0; fn < 4; ++fn)                                           \
        _Pragma("unroll")                                                      \
        for (int r = 0; r < 4; ++r)                                            \
          sf[mf][fn][r] = EXP2F(sf[mf][fn][r] - m_[mf][r]);                    \
    float rsum[2][4];                                                          \
    _Pragma("unroll")                                                          \
    for (int mf = 0; mf < 2; ++mf)                                             \
      _Pragma("unroll")                                                        \
      for (int r = 0; r < 4; ++r)                                              \
        rsum[mf][r] = (sf[mf][0][r] + sf[mf][1][r]) +                          \
                      (sf[mf][2][r] + sf[mf][3][r]);                           \
    _Pragma("unroll")                                                          \
    for (int d = 1; d < 16; d <<= 1)                                           \
      _Pragma("unroll")                                                        \
      for (int mf = 0; mf < 2; ++mf)                                           \
        _Pragma("unroll")                                                      \
        for (int r = 0; r < 4; ++r)                                            \
          rsum[mf][r] += __shfl_xor(rsum[mf][r], d);                           \
    _Pragma("unroll")                                                          \
    for (int mf = 0; mf < 2; ++mf)                                             \
      _Pragma("unroll")                                                        \
      for (int r = 0; r < 4; ++r) l_[mf][r] += rsum[mf][r];                    \
    /* P: C-layout -> LDS -> A-layout (per-wave patch, no barrier) */          \
    _Pragma("unroll")                                                          \
    for (int mf = 0; mf < 2; ++mf)                                             \
      _Pragma("unroll")                                                        \
      for (int fn = 0; fn < 4; ++fn)                                           \
        _Pragma("unroll")                                                      \
        for (int r = 0; r < 4; ++r)                                            \
          Pw[(mf*16 + quad*4 + r)*72 + fn*16 + l16] = (__bf16)sf[mf][fn][r];   \
    bf16x8 pa[2][2];                                                           \
    _Pragma("unroll")                                                          \
    for (int mf = 0; mf < 2; ++mf)                                             \
      _Pragma("unroll")                                                        \
      for (int kq = 0; kq < 2; ++kq)                                           \
        pa[mf][kq] = *(const bf16x8*)&Pw[(mf*16 + l16)*72 + kq*32 + quad*8];   \
    /* O += P V (16 MFMAs) */                                                  \
    _Pragma("unroll")                                                          \
    for (int mf = 0; mf < 2; ++mf)                                             \
      _Pragma("unroll")                                                        \
      for (int nd = 0; nd < 4; ++nd) {                                         \
        of[mf][nd] = MFMA16(pa[mf][0], vf[nd][0], of[mf][nd]);                 \
        of[mf][nd] = MFMA16(pa[mf][1], vf[nd][1], of[mf][nd]);                 \
      }                                                                        \
  }

  for (int kt = wv; kt < ktiles; kt += 8) {
    TILE_STEP(kfA, kfB, kt);
    if (kt + 4 < ktiles) TILE_STEP(kfB, kfA, kt + 4);
  }
#undef TILE_STEP

  // ---- cross-wave combine (log2 domain) ----
  float* cb = (float*)smem;
  __syncthreads();                              // all Pw reads done
  if (wv > 0) {
    float* C = cb + ((wv-1)*64 + lane)*52;      // 48 floats + pad
#pragma unroll
    for (int mf = 0; mf < 2; ++mf)
#pragma unroll
      for (int r = 0; r < 4; ++r) { C[mf*4+r] = m_[mf][r]; C[8+mf*4+r] = l_[mf][r]; }
#pragma unroll
    for (int mf = 0; mf < 2; ++mf)
#pragma unroll
      for (int nd = 0; nd < 4; ++nd)
        *(f32x4*)&C[16 + (mf*4+nd)*4] = of[mf][nd];
  }
  __syncthreads();
  if (wv == 0) {
    // wave 0 always owns k-tile 0 -> m_ finite; empty partials have
    // m=-1e30,l=0,of=0 and contribute exp2(-1e30-mn)=0. No NaN paths.
    for (int wi = 1; wi < 4; ++wi) {
      const float* C = cb + ((wi-1)*64 + lane)*52;
#pragma unroll
      for (int mf = 0; mf < 2; ++mf)
#pragma unroll
        for (int r = 0; r < 4; ++r) {
          const float mo = C[mf*4+r], lo = C[8+mf*4+r];
          const float mn = fmaxf(m_[mf][r], mo);
          const float a  = EXP2F(m_[mf][r] - mn);
          const float bt = EXP2F(mo - mn);
          m_[mf][r] = mn;
          l_[mf][r] = l_[mf][r]*a + lo*bt;
#pragma unroll
          for (int nd = 0; nd < 4; ++nd)
            of[mf][nd][r] = of[mf][nd][r]*a + C[16 + (mf*4+nd)*4 + r]*bt;
        }
    }
    // normalize + store merged-head layout [B, S, H*Dh]
#pragma unroll
    for (int mf = 0; mf < 2; ++mf)
#pragma unroll
      for (int r = 0; r < 4; ++r)
        l_[mf][r] = 1.0f / l_[mf][r];
#pragma unroll
    for (int mf = 0; mf < 2; ++mf)
#pragma unroll
      for (int nd = 0; nd < 4; ++nd) {
        const int dh = nd*16 + l16;
#pragma unroll
        for (int r = 0; r < 4; ++r) {
          const int q = q0 + mf*16 + quad*4 + r;
          attnb[((size_t)b*SEQ + q)*DIM + h*DH + dh] = (__bf16)(of[mf][nd][r] * l_[mf][r]);
        }
      }
  }
}

// ---------------------------------------------------------------------------
extern "C" void kernel_launch(void* const* d_in, const int* in_sizes, int n_in,
                              void* d_out, int out_size, void* d_ws, size_t ws_size,
                              hipStream_t stream) {
  const float* x  = (const float*)d_in[0];
  // d_in[1] = causal mask, unused (causality computed analytically)
  const float* Wq = (const float*)d_in[2];
  const float* bq = (const float*)d_in[3];
  const float* Wk = (const float*)d_in[4];
  const float* bk = (const float*)d_in[5];
  const float* Wv = (const float*)d_in[6];
  const float* bv = (const float*)d_in[7];
  const float* Wo = (const float*)d_in[8];
  const float* bo = (const float*)d_in[9];
  float* out = (float*)d_out;

  // workspace carve-up (bf16 elements), total ~44 MB
  __bf16* xb    = (__bf16*)d_ws;
  __bf16* wq    = xb + (size_t)NTOK*DIM;
  __bf16* wk    = wq + DIM*DIM;
  __bf16* wv    = wk + DIM*DIM;
  __bf16* wo    = wv + DIM*DIM;
  __bf16* Qb    = wo + DIM*DIM;
  __bf16* Kb    = Qb + (size_t)NTOK*DIM;
  __bf16* Vt    = Kb + (size_t)NTOK*DIM;
  __bf16* attnb = Vt + (size_t)NTOK*DIM;

  // converts (2 launches)
  cvt_f32_bf16<<<(NTOK*DIM/8)/256, 256, 0, stream>>>(x, xb, NTOK*DIM/8);
  cvt_weights<<<(4*DIM*DIM/8)/256, 256, 0, stream>>>(Wq, Wk, Wv, Wo, wq, wk, wv, wo);

  // Q/K/V projections
  gemm_qkv<<<dim3(NTOK/128, DIM/128, 3), 256, 0, stream>>>(
      xb, wq, wk, wv, bq, bk, bv, Qb, Kb, Vt);

  // flash attention (4-wave split-K blocks, heavy-first)
  flash_attn<<<2048, 256, 0, stream>>>(Qb, Kb, Vt, attnb);

  // output projection
  gemm_out<<<dim3(NTOK/128, DIM/128), 256, 0, stream>>>(attnb, wo, bo, out);
}

// Round 2
// 213.663 us; speedup vs baseline: 1.1890x; 1.1890x over previous
//
#include <hip/hip_runtime.h>
#include <hip/hip_bf16.h>

// Problem constants (B=4, S=2048, D=512, H=8, Dh=64)
#define BATCH 4
#define SEQ   2048
#define DIM   512
#define NH    8
#define DH    64
#define NTOK  (BATCH*SEQ)        // 8192

typedef __bf16 bf16x8 __attribute__((ext_vector_type(8)));
typedef float  f32x4  __attribute__((ext_vector_type(4)));

#define MFMA16(a,b,c) __builtin_amdgcn_mfma_f32_16x16x32_bf16((a),(b),(c),0,0,0)

#if __has_builtin(__builtin_amdgcn_exp2f)
#define EXP2F(x) __builtin_amdgcn_exp2f(x)
#else
#define EXP2F(x) exp2f(x)
#endif

// Q pre-scaled by log2(e)/8 in the projection epilogue -> softmax in exp2 space
#define QSCALE 0.18033688011112042f

// async global->LDS, 16 B per lane; LDS dest is wave-uniform base (+lane*16)
typedef __attribute__((address_space(1))) void GAS;
typedef __attribute__((address_space(3))) void LAS;
__device__ __forceinline__ void gl_lds16(const void* g, void* l) {
  __builtin_amdgcn_global_load_lds((GAS*)g, (LAS*)l, 16, 0, 0);
}

// ---------------------------------------------------------------------------
// fp32 -> bf16 convert, 8 elems/thread
// ---------------------------------------------------------------------------
__global__ __launch_bounds__(256) void cvt_f32_bf16(const float* __restrict__ src,
                                                    __bf16* __restrict__ dst, int n8) {
  int i = blockIdx.x * blockDim.x + threadIdx.x;
  if (i >= n8) return;
  const float4* s = (const float4*)src;
  float4 a = s[2*i], b = s[2*i+1];
  bf16x8 o;
  o[0] = (__bf16)a.x; o[1] = (__bf16)a.y; o[2] = (__bf16)a.z; o[3] = (__bf16)a.w;
  o[4] = (__bf16)b.x; o[5] = (__bf16)b.y; o[6] = (__bf16)b.z; o[7] = (__bf16)b.w;
  *(bf16x8*)&dst[8*i] = o;
}

__global__ __launch_bounds__(256) void cvt_weights(
    const float* __restrict__ s0, const float* __restrict__ s1,
    const float* __restrict__ s2, const float* __restrict__ s3,
    __bf16* __restrict__ o0, __bf16* __restrict__ o1,
    __bf16* __restrict__ o2, __bf16* __restrict__ o3) {
  int i = blockIdx.x * blockDim.x + threadIdx.x;   // 4 * 32768 chunks of 8
  const int which = i >> 15, off = i & 32767;
  const float* src = (which == 0) ? s0 : (which == 1) ? s1 : (which == 2) ? s2 : s3;
  __bf16* dst      = (which == 0) ? o0 : (which == 1) ? o1 : (which == 2) ? o2 : o3;
  const float4* s = (const float4*)src;
  float4 a = s[2*off], b = s[2*off+1];
  bf16x8 o;
  o[0] = (__bf16)a.x; o[1] = (__bf16)a.y; o[2] = (__bf16)a.z; o[3] = (__bf16)a.w;
  o[4] = (__bf16)b.x; o[5] = (__bf16)b.y; o[6] = (__bf16)b.z; o[7] = (__bf16)b.w;
  *(bf16x8*)&dst[8*off] = o;
}

// ---------------------------------------------------------------------------
// NT GEMM 128x128 tile, m97 structure: global_load_lds (16B) into linear
// LDS [128][64], 4 waves, 4x4 acc/wave.  z = 0/1/2 -> Q / K / V projection.
// Q written pre-scaled by log2e/8 (exp2-space softmax downstream).
// ---------------------------------------------------------------------------
__global__ __launch_bounds__(256) void gemm_qkv(
    const __bf16* __restrict__ xb,
    const __bf16* __restrict__ wq, const __bf16* __restrict__ wk,
    const __bf16* __restrict__ wv,
    const float* __restrict__ bq, const float* __restrict__ bk,
    const float* __restrict__ bv,
    __bf16* __restrict__ Qb, __bf16* __restrict__ Kb, __bf16* __restrict__ Vt)
{
  const int z = blockIdx.z;
  const __bf16* W    = (z == 0) ? wq : (z == 1) ? wk : wv;
  const float*  bias = (z == 0) ? bq : (z == 1) ? bk : bv;

  __shared__ __align__(16) __bf16 As[128*64];
  __shared__ __align__(16) __bf16 Bs[128*64];

  const int tid  = threadIdx.x;
  const int m0   = blockIdx.x * 128, n0 = blockIdx.y * 128;
  const int w    = tid >> 6, lane = tid & 63, quad = lane >> 4, l16 = lane & 15;
  const int wm   = (w >> 1) * 64, wn = (w & 1) * 64;
  const int srow = w*32 + (lane >> 3);
  const int scc  = (lane & 7) * 8;

  f32x4 acc[4][4] = {};

  for (int k0 = 0; k0 < DIM; k0 += 64) {
#pragma unroll
    for (int i = 0; i < 4; ++i) {
      const int row = srow + i*8;
      gl_lds16(&xb[(size_t)(m0+row)*DIM + k0 + scc], &As[(w*4+i)*512]);
      gl_lds16(&W [(size_t)(n0+row)*DIM + k0 + scc], &Bs[(w*4+i)*512]);
    }
    __syncthreads();
#pragma unroll
    for (int kk = 0; kk < 2; ++kk) {
      const int ko = kk*32 + quad*8;
      bf16x8 af[4], bfr[4];
#pragma unroll
      for (int f = 0; f < 4; ++f) {
        af[f]  = *(const bf16x8*)&As[(wm + f*16 + l16)*64 + ko];
        bfr[f] = *(const bf16x8*)&Bs[(wn + f*16 + l16)*64 + ko];
      }
#pragma unroll
      for (int fm = 0; fm < 4; ++fm)
#pragma unroll
        for (int fn = 0; fn < 4; ++fn)
          acc[fm][fn] = MFMA16(af[fm], bfr[fn], acc[fm][fn]);
    }
    __syncthreads();
  }

  // epilogue: C row = m0+wm+fm*16+quad*4+r ; col = n0+wn+fn*16+l16
#pragma unroll
  for (int fm = 0; fm < 4; ++fm) {
#pragma unroll
    for (int fn = 0; fn < 4; ++fn) {
      const int col  = n0 + wn + fn*16 + l16;
      const float bc = bias[col];
      const int h = col >> 6, dh = col & 63;
#pragma unroll
      for (int r = 0; r < 4; ++r) {
        const int row = m0 + wm + fm*16 + quad*4 + r;
        const int b = row >> 11, s = row & 2047;
        const float v = acc[fm][fn][r] + bc;
        if (z == 2) {
          Vt[((size_t)(b*NH + h)*DH + dh)*SEQ + s] = (__bf16)v;
        } else if (z == 0) {
          Qb[((size_t)(b*NH + h)*SEQ + s)*DH + dh] = (__bf16)(v * QSCALE);
        } else {
          Kb[((size_t)(b*NH + h)*SEQ + s)*DH + dh] = (__bf16)v;
        }
      }
    }
  }
}

// ---------------------------------------------------------------------------
// Output projection (same m97-style staging), fp32 out
// ---------------------------------------------------------------------------
__global__ __launch_bounds__(256) void gemm_out(
    const __bf16* __restrict__ attnb, const __bf16* __restrict__ wo,
    const float* __restrict__ bo, float* __restrict__ out)
{
  __shared__ __align__(16) __bf16 As[128*64];
  __shared__ __align__(16) __bf16 Bs[128*64];

  const int tid = threadIdx.x;
  const int m0  = blockIdx.x * 128, n0 = blockIdx.y * 128;
  const int w   = tid >> 6, lane = tid & 63, quad = lane >> 4, l16 = lane & 15;
  const int wm  = (w >> 1) * 64, wn = (w & 1) * 64;
  const int srow = w*32 + (lane >> 3);
  const int scc  = (lane & 7) * 8;

  f32x4 acc[4][4] = {};

  for (int k0 = 0; k0 < DIM; k0 += 64) {
#pragma unroll
    for (int i = 0; i < 4; ++i) {
      const int row = srow + i*8;
      gl_lds16(&attnb[(size_t)(m0+row)*DIM + k0 + scc], &As[(w*4+i)*512]);
      gl_lds16(&wo   [(size_t)(n0+row)*DIM + k0 + scc], &Bs[(w*4+i)*512]);
    }
    __syncthreads();
#pragma unroll
    for (int kk = 0; kk < 2; ++kk) {
      const int ko = kk*32 + quad*8;
      bf16x8 af[4], bfr[4];
#pragma unroll
      for (int f = 0; f < 4; ++f) {
        af[f]  = *(const bf16x8*)&As[(wm + f*16 + l16)*64 + ko];
        bfr[f] = *(const bf16x8*)&Bs[(wn + f*16 + l16)*64 + ko];
      }
#pragma unroll
      for (int fm = 0; fm < 4; ++fm)
#pragma unroll
        for (int fn = 0; fn < 4; ++fn)
          acc[fm][fn] = MFMA16(af[fm], bfr[fn], acc[fm][fn]);
    }
    __syncthreads();
  }

#pragma unroll
  for (int fm = 0; fm < 4; ++fm) {
#pragma unroll
    for (int fn = 0; fn < 4; ++fn) {
      const int col  = n0 + wn + fn*16 + l16;
      const float bc = bo[col];
#pragma unroll
      for (int r = 0; r < 4; ++r) {
        const int row = m0 + wm + fm*16 + quad*4 + r;
        out[(size_t)row*DIM + col] = acc[fm][fn][r] + bc;
      }
    }
  }
}

// ---------------------------------------------------------------------------
// Flash attention v5 = proven v3 structure (2048 one-wave blocks, 32 q-rows,
// 64-key tiles, heavy-first, K register ping-pong, V issued early) plus:
//  - exp2-domain softmax (Q pre-scaled by log2e/8 in projection)
//  - DEFERRED l-reduction: per-lane partial sums, one cross-lane reduce at end
//    (removes the per-step 4-stage sum shuffle tree from the critical chain)
//  - s_setprio(1) around MFMA clusters (m191: +4-7% in this exact regime)
// ---------------------------------------------------------------------------
__global__ __launch_bounds__(64) void flash_attn(
    const __bf16* __restrict__ Qb, const __bf16* __restrict__ Kb,
    const __bf16* __restrict__ Vt, __bf16* __restrict__ attnb)
{
  const int idx = blockIdx.x;
  const int bh  = idx & 31;                    // same-bh blocks share an XCD L2
  const int t   = 63 - (idx >> 5);             // heavy q-tiles dispatch first
  const int b   = bh >> 3, h = bh & 7;
  const int lane = threadIdx.x & 63, quad = lane >> 4, l16 = lane & 15;
  const int q0  = t * 32;

  const __bf16* Qp = Qb + (size_t)bh * SEQ * DH;   // [s][dh], pre-scaled
  const __bf16* Kp = Kb + (size_t)bh * SEQ * DH;   // [s][dh]
  const __bf16* Vp = Vt + (size_t)bh * DH * SEQ;   // [dh][s]

  __shared__ __align__(16) __bf16 Pw[32*72];       // P transpose patch

  // Q fragments (already scaled by log2e/8 at projection)
  bf16x8 qf[2][2];
#pragma unroll
  for (int mf = 0; mf < 2; ++mf)
#pragma unroll
    for (int kk = 0; kk < 2; ++kk)
      qf[mf][kk] = *(const bf16x8*)&Qp[(size_t)(q0 + mf*16 + l16)*DH + kk*32 + quad*8];

  f32x4 of[2][4] = {};
  float m_[2][4], l_[2][4];                    // l_ is a PER-LANE partial
#pragma unroll
  for (int mf = 0; mf < 2; ++mf)
#pragma unroll
    for (int r = 0; r < 4; ++r) { m_[mf][r] = -1e30f; l_[mf][r] = 0.f; }

  const int ktiles = (q0 >> 6) + 1;            // covers keys [0, q0+32)

  bf16x8 kfA[4][2], kfB[4][2];
  // prologue: K tile 0 into buffer A
#pragma unroll
  for (int fn = 0; fn < 4; ++fn)
#pragma unroll
    for (int kk = 0; kk < 2; ++kk)
      kfA[fn][kk] = *(const bf16x8*)&Kp[(size_t)(fn*16 + l16)*DH + kk*32 + quad*8];

#define TILE_STEP(KC, KN, KT)                                                  \
  {                                                                            \
    const int k0 = (KT) * 64;                                                  \
    /* V for this tile — issued first, consumed after softmax */               \
    bf16x8 vf[4][2];                                                           \
    _Pragma("unroll")                                                          \
    for (int nd = 0; nd < 4; ++nd)                                             \
      _Pragma("unroll")                                                        \
      for (int kq = 0; kq < 2; ++kq)                                           \
        vf[nd][kq] = *(const bf16x8*)&Vp[(size_t)(nd*16 + l16)*SEQ + k0 +      \
                                         kq*32 + quad*8];                      \
    /* prefetch next K tile into the other buffer */                           \
    {                                                                          \
      const int kn0 = ((KT) + 1 < ktiles) ? k0 + 64 : 0;                       \
      _Pragma("unroll")                                                        \
      for (int fn = 0; fn < 4; ++fn)                                           \
        _Pragma("unroll")                                                      \
        for (int kk = 0; kk < 2; ++kk)                                         \
          KN[fn][kk] = *(const bf16x8*)&Kp[(size_t)(kn0 + fn*16 + l16)*DH +    \
                                           kk*32 + quad*8];                    \
    }                                                                          \
    /* QK^T (16 MFMAs), scores in log2 domain */                               \
    f32x4 sf[2][4] = {};                                                       \
    __builtin_amdgcn_s_setprio(1);                                             \
    _Pragma("unroll")                                                          \
    for (int mf = 0; mf < 2; ++mf)                                             \
      _Pragma("unroll")                                                        \
      for (int fn = 0; fn < 4; ++fn) {                                         \
        sf[mf][fn] = MFMA16(qf[mf][0], KC[fn][0], sf[mf][fn]);                 \
        sf[mf][fn] = MFMA16(qf[mf][1], KC[fn][1], sf[mf][fn]);                 \
      }                                                                        \
    __builtin_amdgcn_s_setprio(0);                                             \
    /* causal mask (only diagonal-crossing tiles) */                           \
    if (k0 + 63 > q0) {                                                        \
      _Pragma("unroll")                                                        \
      for (int mf = 0; mf < 2; ++mf)                                           \
        _Pragma("unroll")                                                      \
        for (int fn = 0; fn < 4; ++fn) {                                       \
          const int col = k0 + fn*16 + l16;                                    \
          _Pragma("unroll")                                                    \
          for (int r = 0; r < 4; ++r) {                                        \
            const int row = q0 + mf*16 + quad*4 + r;                           \
            if (col > row) sf[mf][fn][r] = -1e30f;                             \
          }                                                                    \
        }                                                                      \
    }                                                                          \
    /* online softmax (exp2 space): max reduce across the 16-lane group */     \
    float rmax[2][4];                                                          \
    _Pragma("unroll")                                                          \
    for (int mf = 0; mf < 2; ++mf)                                             \
      _Pragma("unroll")                                                        \
      for (int r = 0; r < 4; ++r)                                              \
        rmax[mf][r] = fmaxf(fmaxf(sf[mf][0][r], sf[mf][1][r]),                 \
                            fmaxf(sf[mf][2][r], sf[mf][3][r]));                \
    _Pragma("unroll")                                                          \
    for (int d = 1; d < 16; d <<= 1)                                           \
      _Pragma("unroll")                                                        \
      for (int mf = 0; mf < 2; ++mf)                                           \
        _Pragma("unroll")                                                      \
        for (int r = 0; r < 4; ++r)                                            \
          rmax[mf][r] = fmaxf(rmax[mf][r], __shfl_xor(rmax[mf][r], d));        \
    /* rescale + exp2; l stays PER-LANE (deferred reduction) */                \
    _Pragma("unroll")                                                          \
    for (int mf = 0; mf < 2; ++mf)                                             \
      _Pragma("unroll")                                                        \
      for (int r = 0; r < 4; ++r) {                                            \
        const float mn = fmaxf(m_[mf][r], rmax[mf][r]);                        \
        const float al = EXP2F(m_[mf][r] - mn);                                \
        m_[mf][r] = mn;                                                        \
        l_[mf][r] *= al;                                                       \
        _Pragma("unroll")                                                      \
        for (int nd = 0; nd < 4; ++nd) of[mf][nd][r] *= al;                    \
      }                                                                        \
    _Pragma("unroll")                                                          \
    for (int mf = 0; mf < 2; ++mf)                                             \
      _Pragma("unroll")                                                        \
      for (int fn = 0; fn < 4; ++fn)                                           \
        _Pragma("unroll")                                                      \
        for (int r = 0; r < 4; ++r)                                            \
          sf[mf][fn][r] = EXP2F(sf[mf][fn][r] - m_[mf][r]);                    \
    _Pragma("unroll")                                                          \
    for (int mf = 0; mf < 2; ++mf)                                             \
      _Pragma("unroll")                                                        \
      for (int r = 0; r < 4; ++r)                                              \
        l_[mf][r] += (sf[mf][0][r] + sf[mf][1][r]) +                           \
                     (sf[mf][2][r] + sf[mf][3][r]);                            \
    /* P: C-layout -> LDS -> A-layout */                                       \
    _Pragma("unroll")                                                          \
    for (int mf = 0; mf < 2; ++mf)                                             \
      _Pragma("unroll")                                                        \
      for (int fn = 0; fn < 4; ++fn)                                           \
        _Pragma("unroll")                                                      \
        for (int r = 0; r < 4; ++r)                                            \
          Pw[(mf*16 + quad*4 + r)*72 + fn*16 + l16] = (__bf16)sf[mf][fn][r];   \
    bf16x8 pa[2][2];                                                           \
    _Pragma("unroll")                                                          \
    for (int mf = 0; mf < 2; ++mf)                                             \
      _Pragma("unroll")                                                        \
      for (int kq = 0; kq < 2; ++kq)                                           \
        pa[mf][kq] = *(const bf16x8*)&Pw[(mf*16 + l16)*72 + kq*32 + quad*8];   \
    /* O += P V (16 MFMAs) */                                                  \
    __builtin_amdgcn_s_setprio(1);                                             \
    _Pragma("unroll")                                                          \
    for (int mf = 0; mf < 2; ++mf)                                             \
      _Pragma("unroll")                                                        \
      for (int nd = 0; nd < 4; ++nd) {                                         \
        of[mf][nd] = MFMA16(pa[mf][0], vf[nd][0], of[mf][nd]);                 \
        of[mf][nd] = MFMA16(pa[mf][1], vf[nd][1], of[mf][nd]);                 \
      }                                                                        \
    __builtin_amdgcn_s_setprio(0);                                             \
  }

  for (int kt = 0; kt < ktiles; kt += 2) {
    TILE_STEP(kfA, kfB, kt);
    if (kt + 1 < ktiles) TILE_STEP(kfB, kfA, kt + 1);
  }
#undef TILE_STEP

  // ---- deferred l reduction (once), then normalize + store ----
#pragma unroll
  for (int d = 1; d < 16; d <<= 1)
#pragma unroll
    for (int mf = 0; mf < 2; ++mf)
#pragma unroll
      for (int r = 0; r < 4; ++r)
        l_[mf][r] += __shfl_xor(l_[mf][r], d);
#pragma unroll
  for (int mf = 0; mf < 2; ++mf)
#pragma unroll
    for (int r = 0; r < 4; ++r)
      l_[mf][r] = 1.0f / l_[mf][r];
#pragma unroll
  for (int mf = 0; mf < 2; ++mf)
#pragma unroll
    for (int nd = 0; nd < 4; ++nd) {
      const int dh = nd*16 + l16;
#pragma unroll
      for (int r = 0; r < 4; ++r) {
        const int q = q0 + mf*16 + quad*4 + r;
        attnb[((size_t)b*SEQ + q)*DIM + h*DH + dh] = (__bf16)(of[mf][nd][r] * l_[mf][r]);
      }
    }
}

// ---------------------------------------------------------------------------
extern "C" void kernel_launch(void* const* d_in, const int* in_sizes, int n_in,
                              void* d_out, int out_size, void* d_ws, size_t ws_size,
                              hipStream_t stream) {
  const float* x  = (const float*)d_in[0];
  // d_in[1] = causal mask, unused (causality computed analytically)
  const float* Wq = (const float*)d_in[2];
  const float* bq = (const float*)d_in[3];
  const float* Wk = (const float*)d_in[4];
  const float* bk = (const float*)d_in[5];
  const float* Wv = (const float*)d_in[6];
  const float* bv = (const float*)d_in[7];
  const float* Wo = (const float*)d_in[8];
  const float* bo = (const float*)d_in[9];
  float* out = (float*)d_out;

  // workspace carve-up (bf16 elements), total ~44 MB
  __bf16* xb    = (__bf16*)d_ws;
  __bf16* wq    = xb + (size_t)NTOK*DIM;
  __bf16* wk    = wq + DIM*DIM;
  __bf16* wv    = wk + DIM*DIM;
  __bf16* wo    = wv + DIM*DIM;
  __bf16* Qb    = wo + DIM*DIM;
  __bf16* Kb    = Qb + (size_t)NTOK*DIM;
  __bf16* Vt    = Kb + (size_t)NTOK*DIM;
  __bf16* attnb = Vt + (size_t)NTOK*DIM;

  // converts (2 launches)
  cvt_f32_bf16<<<(NTOK*DIM/8)/256, 256, 0, stream>>>(x, xb, NTOK*DIM/8);
  cvt_weights<<<(4*DIM*DIM/8)/256, 256, 0, stream>>>(Wq, Wk, Wv, Wo, wq, wk, wv, wo);

  // Q/K/V projections
  gemm_qkv<<<dim3(NTOK/128, DIM/128, 3), 256, 0, stream>>>(
      xb, wq, wk, wv, bq, bk, bv, Qb, Kb, Vt);

  // flash attention (one-wave blocks, heavy-first)
  flash_attn<<<2048, 64, 0, stream>>>(Qb, Kb, Vt, attnb);

  // output projection
  gemm_out<<<dim3(NTOK/128, DIM/128), 256, 0, stream>>>(attnb, wo, bo, out);
}